// Round 4
// baseline (678.077 us; speedup 1.0000x reference)
//
#include <hip/hip_runtime.h>
#include <hip/hip_bf16.h>

typedef __attribute__((ext_vector_type(8))) short bf16x8;
typedef __attribute__((ext_vector_type(4))) float f32x4;

#define CIN 64
#define COUT 64
#define NK 64
#define SLABK 16             // kernels per z-slab
#define SLABCOL 1024         // SLABK * COUT
#define EPSV 1e-5f
#define ENC_NEG_INF 0x007FFFFFu

__device__ __forceinline__ unsigned encf(float f) {
    unsigned b = __float_as_uint(f);
    return (b & 0x80000000u) ? ~b : (b | 0x80000000u);
}
__device__ __forceinline__ float decf(unsigned u) {
    unsigned b = (u & 0x80000000u) ? (u & 0x7FFFFFFFu) : ~u;
    return __uint_as_float(b);
}

// ---------------------------------------------------------------------------
// Kernel 0a: transpose weight [k][c][d] fp32 -> wt [k][d][c] bf16
// ---------------------------------------------------------------------------
__global__ __launch_bounds__(256) void transpose_w_kernel(
    const float* __restrict__ w, __hip_bfloat16* __restrict__ wt) {
    int i = blockIdx.x * 256 + threadIdx.x;          // 262144 total
    int k = i >> 12, r = i & 4095, d = r >> 6, c = r & 63;
    wt[i] = __float2bfloat16(w[(k << 12) + (c << 6) + d]);
}

// Kernel 0b: transpose root [c][d] fp32 -> rt [d][c] bf16 (4096 elems)
__global__ __launch_bounds__(256) void transpose_root_kernel(
    const float* __restrict__ root, __hip_bfloat16* __restrict__ rt) {
    int i = blockIdx.x * 256 + threadIdx.x;
    int d = i >> 6, c = i & 63;
    rt[i] = __float2bfloat16(root[c * 64 + d]);
}

// ---------------------------------------------------------------------------
// CSR build: histogram -> scan -> scatter packed edge records
// record: x = src | base<<17 | l2i<<21 ; y = t0 | t1<<16 (16b fixed) ; z = t2
// ---------------------------------------------------------------------------
__global__ __launch_bounds__(256) void hist_kernel(
    const int* __restrict__ ei, int* __restrict__ deg, int E) {
    int e = blockIdx.x * 256 + threadIdx.x;
    if (e < E) atomicAdd(&deg[ei[E + e]], 1);
}

__global__ __launch_bounds__(1024) void scanA_kernel(
    const int* __restrict__ deg, int* __restrict__ psum, int n) {
    __shared__ int s[1024];
    int i = blockIdx.x * 1024 + threadIdx.x;
    s[threadIdx.x] = (i < n) ? deg[i] : 0;
    __syncthreads();
    for (int st = 512; st > 0; st >>= 1) {
        if (threadIdx.x < st) s[threadIdx.x] += s[threadIdx.x + st];
        __syncthreads();
    }
    if (threadIdx.x == 0) psum[blockIdx.x] = s[0];
}

__global__ void scanB_kernel(int* __restrict__ psum, int nb,
                             int* __restrict__ off, int n) {
    if (threadIdx.x == 0) {
        int run = 0;
        for (int b = 0; b < nb; ++b) { int v = psum[b]; psum[b] = run; run += v; }
        off[n] = run;
    }
}

__global__ __launch_bounds__(1024) void scanC_kernel(
    const int* __restrict__ deg, const int* __restrict__ psum,
    int* __restrict__ off, int* __restrict__ cur, int n) {
    __shared__ int s[1024];
    int tid = threadIdx.x, i = blockIdx.x * 1024 + tid;
    int v = (i < n) ? deg[i] : 0;
    s[tid] = v;
    for (int st = 1; st < 1024; st <<= 1) {
        __syncthreads();
        int t = (tid >= st) ? s[tid - st] : 0;
        __syncthreads();
        s[tid] += t;
    }
    __syncthreads();
    int excl = s[tid] - v + psum[blockIdx.x];
    if (i < n) { off[i] = excl; cur[i] = excl; }
}

__global__ __launch_bounds__(256) void scatter_kernel(
    const int* __restrict__ ei, const float* __restrict__ ea,
    int* __restrict__ cur, uint3* __restrict__ rec, int E) {
    int e = blockIdx.x * 256 + threadIdx.x;
    if (e >= E) return;
    int src = ei[e], dst = ei[E + e];
    float f0 = ea[e * 3 + 0] * 3.f;
    float f1 = ea[e * 3 + 1] * 3.f;
    float f2 = ea[e * 3 + 2] * 3.f;
    float l0 = fminf(fmaxf(floorf(f0), 0.f), 2.f);
    float l1 = fminf(fmaxf(floorf(f1), 0.f), 2.f);
    float l2 = fminf(fmaxf(floorf(f2), 0.f), 2.f);
    unsigned q0 = (unsigned)((f0 - l0) * 65536.f);
    unsigned q1 = (unsigned)((f1 - l1) * 65536.f);
    unsigned q2 = (unsigned)((f2 - l2) * 65536.f);
    int base = (int)l0 + 4 * (int)l1;
    uint3 r;
    r.x = (unsigned)src | ((unsigned)base << 17) | ((unsigned)(int)l2 << 21);
    r.y = q0 | (q1 << 16);
    r.z = q2;
    int pos = atomicAdd(&cur[dst], 1);
    rec[pos] = r;
}

// ---------------------------------------------------------------------------
// Kernel 1: slab GEMM  xwc[n][kk][d] = sum_c x[n][c]*W[k0+kk][c][d], kk<16
// A staged once in LDS; B fragments loaded straight from global (L2-resident,
// 16-B contiguous rows of wt). No per-kk barriers.
// ---------------------------------------------------------------------------
__global__ __launch_bounds__(256) void gemm_xw_kernel(
    const float* __restrict__ x, const __hip_bfloat16* __restrict__ wt,
    __hip_bfloat16* __restrict__ xwc, int nNodes, int k0) {
    __shared__ __attribute__((aligned(16))) __hip_bfloat16 As[128 * 72];

    const int tid  = threadIdx.x;
    const int wave = tid >> 6, lane = tid & 63;
    const int quad = lane >> 4, l16 = lane & 15;
    const int row0 = blockIdx.x * 128;

    for (int i = 0; i < 32; ++i) {
        int idx = tid + i * 256;
        int r = idx >> 6, c = idx & 63;
        float v = (row0 + r < nNodes) ? x[(size_t)(row0 + r) * CIN + c] : 0.f;
        As[r * 72 + c] = __float2bfloat16(v);
    }
    __syncthreads();

    bf16x8 afrag[2][2];
    for (int ks = 0; ks < 2; ++ks)
        for (int mi = 0; mi < 2; ++mi)
            afrag[ks][mi] =
                *(const bf16x8*)&As[(wave * 32 + mi * 16 + l16) * 72 + ks * 32 + quad * 8];

    for (int kk = 0; kk < SLABK; ++kk) {
        const __hip_bfloat16* wk = wt + (size_t)(k0 + kk) * 4096;
        f32x4 acc[2][4] = {};
#pragma unroll
        for (int ks = 0; ks < 2; ++ks) {
            int kb = ks * 32 + quad * 8;
            bf16x8 bfrag[4];
#pragma unroll
            for (int ni = 0; ni < 4; ++ni)
                bfrag[ni] = *(const bf16x8*)&wk[(ni * 16 + l16) * 64 + kb];
#pragma unroll
            for (int mi = 0; mi < 2; ++mi)
#pragma unroll
                for (int ni = 0; ni < 4; ++ni)
                    acc[mi][ni] = __builtin_amdgcn_mfma_f32_16x16x32_bf16(
                        afrag[ks][mi], bfrag[ni], acc[mi][ni], 0, 0, 0);
        }
        // C/D layout: col = lane&15, row = quad*4 + reg
#pragma unroll
        for (int mi = 0; mi < 2; ++mi)
#pragma unroll
            for (int ni = 0; ni < 4; ++ni)
#pragma unroll
                for (int r = 0; r < 4; ++r) {
                    int m = row0 + wave * 32 + mi * 16 + quad * 4 + r;
                    if (m < nNodes)
                        xwc[(size_t)m * SLABCOL + kk * 64 + ni * 16 + l16] =
                            __float2bfloat16(acc[mi][ni][r]);
                }
    }
}

// ---------------------------------------------------------------------------
// Kernel 1b: xroot[n][d] = sum_c x[n][c] * root[c][d]  (fp32 out, MFMA)
// ---------------------------------------------------------------------------
__global__ __launch_bounds__(256) void gemm_root_kernel(
    const float* __restrict__ x, const __hip_bfloat16* __restrict__ rt,
    float* __restrict__ xroot, int nNodes) {
    __shared__ __attribute__((aligned(16))) __hip_bfloat16 As[128 * 72];

    const int tid  = threadIdx.x;
    const int wave = tid >> 6, lane = tid & 63;
    const int quad = lane >> 4, l16 = lane & 15;
    const int row0 = blockIdx.x * 128;

    for (int i = 0; i < 32; ++i) {
        int idx = tid + i * 256;
        int r = idx >> 6, c = idx & 63;
        float v = (row0 + r < nNodes) ? x[(size_t)(row0 + r) * CIN + c] : 0.f;
        As[r * 72 + c] = __float2bfloat16(v);
    }
    __syncthreads();

    f32x4 acc[2][4] = {};
#pragma unroll
    for (int ks = 0; ks < 2; ++ks) {
        int kb = ks * 32 + quad * 8;
        bf16x8 afrag[2], bfrag[4];
        for (int mi = 0; mi < 2; ++mi)
            afrag[mi] = *(const bf16x8*)&As[(wave * 32 + mi * 16 + l16) * 72 + kb];
        for (int ni = 0; ni < 4; ++ni)
            bfrag[ni] = *(const bf16x8*)&rt[(ni * 16 + l16) * 64 + kb];
        for (int mi = 0; mi < 2; ++mi)
            for (int ni = 0; ni < 4; ++ni)
                acc[mi][ni] = __builtin_amdgcn_mfma_f32_16x16x32_bf16(
                    afrag[mi], bfrag[ni], acc[mi][ni], 0, 0, 0);
    }
#pragma unroll
    for (int mi = 0; mi < 2; ++mi)
        for (int ni = 0; ni < 4; ++ni)
            for (int r = 0; r < 4; ++r) {
                int m = row0 + wave * 32 + mi * 16 + quad * 4 + r;
                if (m < nNodes)
                    xroot[(size_t)m * 64 + ni * 16 + l16] = acc[mi][ni][r];
            }
}

// ---------------------------------------------------------------------------
// Kernel 2: per-dst aggregation for one z-slab. One wave per dst node.
// ---------------------------------------------------------------------------
__global__ __launch_bounds__(256) void agg_kernel(
    const uint3* __restrict__ rec, const int* __restrict__ off,
    const __hip_bfloat16* __restrict__ xwc, float* __restrict__ agg,
    int nNodes, int slab) {
    int dst  = (blockIdx.x * 256 + threadIdx.x) >> 6;
    int lane = threadIdx.x & 63;
    if (dst >= nNodes) return;

    int s0 = __builtin_amdgcn_readfirstlane(off[dst]);
    int e0 = __builtin_amdgcn_readfirstlane(off[dst + 1]);

    float acc = 0.f;
    auto contrib = [&](uint3 r) {
        int l2i = (int)((r.x >> 21) & 3u);
        int d = l2i - slab;
        if (d != 0 && d != -1) return;               // wave-uniform skip
        float t2 = (float)(r.z & 0xffffu) * (1.f / 65536.f);
        float zw = (d == 0) ? 1.f - t2 : t2;
        int src  = (int)(r.x & 0x1ffffu);
        int base = (int)((r.x >> 17) & 15u);
        float t0 = (float)(r.y & 0xffffu) * (1.f / 65536.f);
        float t1 = (float)(r.y >> 16) * (1.f / 65536.f);
        float u0 = 1.f - t0, u1 = 1.f - t1;
        const __hip_bfloat16* p = xwc + (size_t)src * SLABCOL + base * 64 + lane;
        acc += zw * (u0 * u1 * __bfloat162float(p[0])
                   + t0 * u1 * __bfloat162float(p[64])
                   + u0 * t1 * __bfloat162float(p[256])
                   + t0 * t1 * __bfloat162float(p[320]));
    };

    int j = s0;
    while (j + 1 < e0) {
        uint3 r0 = rec[j];
        uint3 r1 = rec[j + 1];
        j += 2;
        contrib(r0);
        contrib(r1);
    }
    if (j < e0) contrib(rec[j]);

    float* dp = &agg[(size_t)dst * COUT + lane];
    if (slab == 0) *dp = acc;
    else           *dp += acc;
}

// ---------------------------------------------------------------------------
// Kernel 3: h = elu(agg/max(deg,1) + xroot + bias); accumulate BN sums
// Pure element-wise + per-channel partial reduction.
// ---------------------------------------------------------------------------
__global__ __launch_bounds__(256) void node_kernel(
    const float* __restrict__ xroot, const float* __restrict__ agg,
    const int* __restrict__ deg, const float* __restrict__ bias,
    float* __restrict__ h, float* __restrict__ gstat, int nNodes) {
    __shared__ float red[8][64];
    int tid = threadIdx.x, wave = tid >> 6, lane = tid & 63;
    float b = bias[lane];                     // stride ≡ 0 mod 64 → fixed channel
    float s = 0.f, s2 = 0.f;
    int total = nNodes * 64;
    for (int i = blockIdx.x * 256 + tid; i < total; i += gridDim.x * 256) {
        int n = i >> 6;
        float acc = b + xroot[i] + agg[i] / fmaxf((float)deg[n], 1.f);
        float hv = acc > 0.f ? acc : expm1f(acc);
        h[i] = hv;
        s += hv; s2 += hv * hv;
    }
    red[wave][lane] = s;
    red[4 + wave][lane] = s2;
    __syncthreads();
    if (tid < 64) {
        atomicAdd(&gstat[tid], red[0][tid] + red[1][tid] + red[2][tid] + red[3][tid]);
    } else if (tid < 128) {
        int d = tid - 64;
        atomicAdd(&gstat[64 + d], red[4][d] + red[5][d] + red[6][d] + red[7][d]);
    }
}

// ---------------------------------------------------------------------------
// Kernel 4: finalize BN scale/shift
// ---------------------------------------------------------------------------
__global__ void stats_kernel(const float* __restrict__ gamma,
                             const float* __restrict__ beta,
                             float* __restrict__ gstat, int nNodes) {
    int d = threadIdx.x;
    float invn = 1.f / (float)nNodes;
    float mean = gstat[d] * invn;
    float var  = gstat[64 + d] * invn - mean * mean;
    float sc   = gamma[d] * rsqrtf(var + EPSV);
    gstat[128 + d] = sc;
    gstat[192 + d] = beta[d] - mean * sc;
}

// ---------------------------------------------------------------------------
__global__ __launch_bounds__(256) void initpool_kernel(unsigned* __restrict__ out, int total) {
    int i = blockIdx.x * 256 + threadIdx.x;
    if (i < total) out[i] = ENC_NEG_INF;
}

__global__ __launch_bounds__(256) void pool_kernel(
    const float* __restrict__ h, const float* __restrict__ pos,
    const int* __restrict__ batch, const float* __restrict__ gstat,
    unsigned* __restrict__ out, int nNodes) {
    int gid = blockIdx.x * 256 + threadIdx.x;
    int n = gid >> 6, d = gid & 63;
    if (n >= nNodes) return;
    float v = h[gid] * gstat[128 + d] + gstat[192 + d];
    int v0 = min(max((int)floorf(pos[n * 3 + 0] * (1.f / 32.f)), 0), 7);
    int v1 = min(max((int)floorf(pos[n * 3 + 1] * (1.f / 32.f)), 0), 7);
    int v2 = min(max((int)floorf(pos[n * 3 + 2] * (1.f / 32.f)), 0), 7);
    int cl = batch[n] * 512 + v0 * 64 + v1 * 8 + v2;
    atomicMax(&out[cl * 64 + d], encf(v));
}

__global__ __launch_bounds__(256) void decode_kernel(unsigned* __restrict__ out, int total) {
    int i = blockIdx.x * 256 + threadIdx.x;
    if (i >= total) return;
    float f = decf(out[i]);
    if (!isfinite(f)) f = 0.f;
    ((float*)out)[i] = f;
}

// ---------------------------------------------------------------------------
extern "C" void kernel_launch(void* const* d_in, const int* in_sizes, int n_in,
                              void* d_out, int out_size, void* d_ws, size_t ws_size,
                              hipStream_t stream) {
    const float* x     = (const float*)d_in[0];
    const int*   ei    = (const int*)d_in[1];
    const float* ea    = (const float*)d_in[2];
    const float* pos   = (const float*)d_in[3];
    const int*   batch = (const int*)d_in[4];
    const float* w     = (const float*)d_in[5];
    const float* root  = (const float*)d_in[6];
    const float* bias  = (const float*)d_in[7];
    const float* gamma = (const float*)d_in[8];
    const float* beta  = (const float*)d_in[9];

    const int N = in_sizes[0] / CIN;     // 50000
    const int E = in_sizes[1] / 2;       // 800000

    // workspace carve-up (~126 MB; h and xroot alias the dead xwc buffer)
    char* ws = (char*)d_ws;
    size_t off_b = 0;
    auto carve = [&](size_t bytes) -> char* {
        char* p = ws + off_b;
        off_b = (off_b + bytes + 255) & ~(size_t)255;
        return p;
    };
    __hip_bfloat16* xwc = (__hip_bfloat16*)carve((size_t)N * SLABCOL * 2);  // 102.4 MB
    __hip_bfloat16* wt  = (__hip_bfloat16*)carve((size_t)(NK + 1) * CIN * COUT * 2);
    float*          agg = (float*)carve((size_t)N * COUT * 4);              // 12.8 MB
    int*            deg = (int*)carve((size_t)N * 4);
    int*            off = (int*)carve((size_t)(N + 1) * 4);
    int*            cur = (int*)carve((size_t)N * 4);
    int*            psum = (int*)carve(64 * 4);
    uint3*          rec = (uint3*)carve((size_t)E * 12);                    // 9.6 MB
    float*          gst = (float*)carve(256 * 4);
    // aliases into xwc (dead after last agg pass):
    float*          h     = (float*)xwc;                                    // 12.8 MB
    float*          xroot = (float*)((char*)xwc + ((size_t)N * COUT * 4 + 4096));
    __hip_bfloat16* rt    = wt + (size_t)NK * CIN * COUT;                   // root^T bf16

    hipMemsetAsync(deg, 0, (size_t)N * 4, stream);
    hipMemsetAsync(gst, 0, 256 * 4, stream);

    transpose_w_kernel<<<(NK * CIN * COUT) / 256, 256, 0, stream>>>(w, wt);
    transpose_root_kernel<<<16, 256, 0, stream>>>(root, rt);

    // CSR build
    const int nScan = (N + 1023) / 1024;
    hist_kernel<<<(E + 255) / 256, 256, 0, stream>>>(ei, deg, E);
    scanA_kernel<<<nScan, 1024, 0, stream>>>(deg, psum, N);
    scanB_kernel<<<1, 64, 0, stream>>>(psum, nScan, off, N);
    scanC_kernel<<<nScan, 1024, 0, stream>>>(deg, psum, off, cur, N);
    scatter_kernel<<<(E + 255) / 256, 256, 0, stream>>>(ei, ea, cur, rec, E);

    const int ggrid = (N + 127) / 128;
    const int agrid = (N * 64 + 255) / 256;
    for (int slab = 0; slab < 4; ++slab) {
        gemm_xw_kernel<<<ggrid, 256, 0, stream>>>(x, wt, xwc, N, slab * SLABK);
        agg_kernel<<<agrid, 256, 0, stream>>>(rec, off, xwc, agg, N, slab);
    }

    gemm_root_kernel<<<ggrid, 256, 0, stream>>>(x, rt, xroot, N);

    node_kernel<<<1024, 256, 0, stream>>>(xroot, agg, deg, bias, h, gst, N);

    stats_kernel<<<1, 64, 0, stream>>>(gamma, beta, gst, N);

    initpool_kernel<<<(out_size + 255) / 256, 256, 0, stream>>>((unsigned*)d_out, out_size);

    pool_kernel<<<((size_t)N * COUT + 255) / 256, 256, 0, stream>>>(
        h, pos, batch, gst, (unsigned*)d_out, N);

    decode_kernel<<<(out_size + 255) / 256, 256, 0, stream>>>((unsigned*)d_out, out_size);
}

// Round 5
// 675.899 us; speedup vs baseline: 1.0032x; 1.0032x over previous
//
#include <hip/hip_runtime.h>
#include <hip/hip_bf16.h>

typedef __attribute__((ext_vector_type(8))) short bf16x8;
typedef __attribute__((ext_vector_type(4))) float f32x4;

#define CIN 64
#define COUT 64
#define NK 64
#define SLABK 16             // kernels per z-slab (one kz plane, 4x4 xy)
#define SLABCOL 1024         // SLABK * COUT
#define EPSV 1e-5f
#define ENC_NEG_INF 0x007FFFFFu

__device__ __forceinline__ unsigned encf(float f) {
    unsigned b = __float_as_uint(f);
    return (b & 0x80000000u) ? ~b : (b | 0x80000000u);
}
__device__ __forceinline__ float decf(unsigned u) {
    unsigned b = (u & 0x80000000u) ? (u & 0x7FFFFFFFu) : ~u;
    return __uint_as_float(b);
}

// ---------------------------------------------------------------------------
// Kernel 0a: transpose weight [k][c][d] fp32 -> wt [k][d][c] bf16
// ---------------------------------------------------------------------------
__global__ __launch_bounds__(256) void transpose_w_kernel(
    const float* __restrict__ w, __hip_bfloat16* __restrict__ wt) {
    int i = blockIdx.x * 256 + threadIdx.x;          // 262144 total
    int k = i >> 12, r = i & 4095, d = r >> 6, c = r & 63;
    wt[i] = __float2bfloat16(w[(k << 12) + (c << 6) + d]);
}

// Kernel 0b: transpose root [c][d] fp32 -> rt [d][c] bf16
__global__ __launch_bounds__(256) void transpose_root_kernel(
    const float* __restrict__ root, __hip_bfloat16* __restrict__ rt) {
    int i = blockIdx.x * 256 + threadIdx.x;
    int d = i >> 6, c = i & 63;
    rt[i] = __float2bfloat16(root[c * 64 + d]);
}

// ---------------------------------------------------------------------------
// CSR build, z-grouped: per-dst per-l2i histogram -> scan -> scatter 8-B recs
// rec: x = src | base<<17 | q2<<21 ; y = q0 | q1<<11   (11-bit fixed t's)
// ---------------------------------------------------------------------------
__global__ __launch_bounds__(256) void hist_kernel(
    const int* __restrict__ ei, const float* __restrict__ ea,
    int* __restrict__ degz, int E) {
    int e = blockIdx.x * 256 + threadIdx.x;
    if (e >= E) return;
    int dst = ei[E + e];
    float f2 = ea[e * 3 + 2] * 3.f;
    int l2i = (int)fminf(fmaxf(floorf(f2), 0.f), 2.f);
    atomicAdd(&degz[dst * 4 + l2i], 1);
}

__global__ __launch_bounds__(1024) void scanA_kernel(
    const int4* __restrict__ degz, int* __restrict__ psum, int n) {
    __shared__ int s[1024];
    int i = blockIdx.x * 1024 + threadIdx.x;
    int v = 0;
    if (i < n) { int4 d = degz[i]; v = d.x + d.y + d.z; }
    s[threadIdx.x] = v;
    __syncthreads();
    for (int st = 512; st > 0; st >>= 1) {
        if (threadIdx.x < st) s[threadIdx.x] += s[threadIdx.x + st];
        __syncthreads();
    }
    if (threadIdx.x == 0) psum[blockIdx.x] = s[0];
}

__global__ void scanB_kernel(int* __restrict__ psum, int nb) {
    if (threadIdx.x == 0) {
        int run = 0;
        for (int b = 0; b < nb; ++b) { int v = psum[b]; psum[b] = run; run += v; }
    }
}

__global__ __launch_bounds__(1024) void scanC_kernel(
    const int4* __restrict__ degz, const int* __restrict__ psum,
    int* __restrict__ grpoff, int* __restrict__ cur4, int n) {
    __shared__ int s[1024];
    int tid = threadIdx.x, i = blockIdx.x * 1024 + tid;
    int4 d = make_int4(0, 0, 0, 0);
    if (i < n) d = degz[i];
    int v = d.x + d.y + d.z;
    s[tid] = v;
    for (int st = 1; st < 1024; st <<= 1) {
        __syncthreads();
        int t = (tid >= st) ? s[tid - st] : 0;
        __syncthreads();
        s[tid] += t;
    }
    __syncthreads();
    int excl = s[tid] - v + psum[blockIdx.x];
    if (i < n) {
        grpoff[4 * i + 0] = excl;
        grpoff[4 * i + 1] = excl + d.x;
        grpoff[4 * i + 2] = excl + d.x + d.y;
        grpoff[4 * i + 3] = excl + v;
        cur4[4 * i + 0] = excl;
        cur4[4 * i + 1] = excl + d.x;
        cur4[4 * i + 2] = excl + d.x + d.y;
    }
}

__global__ __launch_bounds__(256) void scatter_kernel(
    const int* __restrict__ ei, const float* __restrict__ ea,
    int* __restrict__ cur4, uint2* __restrict__ rec, int E) {
    int e = blockIdx.x * 256 + threadIdx.x;
    if (e >= E) return;
    int src = ei[e], dst = ei[E + e];
    float f0 = ea[e * 3 + 0] * 3.f;
    float f1 = ea[e * 3 + 1] * 3.f;
    float f2 = ea[e * 3 + 2] * 3.f;
    float l0 = fminf(fmaxf(floorf(f0), 0.f), 2.f);
    float l1 = fminf(fmaxf(floorf(f1), 0.f), 2.f);
    float l2 = fminf(fmaxf(floorf(f2), 0.f), 2.f);
    unsigned q0 = (unsigned)((f0 - l0) * 2048.f);
    unsigned q1 = (unsigned)((f1 - l1) * 2048.f);
    unsigned q2 = (unsigned)((f2 - l2) * 2048.f);
    int base = (int)l0 + 4 * (int)l1;
    int l2i = (int)l2;
    uint2 r;
    r.x = (unsigned)src | ((unsigned)base << 17) | (q2 << 21);
    r.y = q0 | (q1 << 11);
    int pos = atomicAdd(&cur4[dst * 4 + l2i], 1);
    rec[pos] = r;
}

// ---------------------------------------------------------------------------
// Kernel 1: slab GEMM, M-tile = 64 rows (782 blocks -> ~12 waves/CU).
// A staged in LDS once; B fragments direct from global (L2-hot).
// ---------------------------------------------------------------------------
__global__ __launch_bounds__(256) void gemm_xw_kernel(
    const float* __restrict__ x, const __hip_bfloat16* __restrict__ wt,
    __hip_bfloat16* __restrict__ xwc, int nNodes, int k0) {
    __shared__ __attribute__((aligned(16))) __hip_bfloat16 As[64 * 72];

    const int tid  = threadIdx.x;
    const int wave = tid >> 6, lane = tid & 63;
    const int quad = lane >> 4, l16 = lane & 15;
    const int row0 = blockIdx.x * 64;

    for (int i = 0; i < 16; ++i) {
        int idx = tid + i * 256;
        int r = idx >> 6, c = idx & 63;
        float v = (row0 + r < nNodes) ? x[(size_t)(row0 + r) * CIN + c] : 0.f;
        As[r * 72 + c] = __float2bfloat16(v);
    }
    __syncthreads();

    bf16x8 afrag[2];
#pragma unroll
    for (int ks = 0; ks < 2; ++ks)
        afrag[ks] = *(const bf16x8*)&As[(wave * 16 + l16) * 72 + ks * 32 + quad * 8];

    const int mrow = row0 + wave * 16 + quad * 4;

    for (int kk = 0; kk < SLABK; ++kk) {
        const __hip_bfloat16* wk = wt + (size_t)(k0 + kk) * 4096;
        f32x4 acc[4] = {};
#pragma unroll
        for (int ks = 0; ks < 2; ++ks) {
            int kb = ks * 32 + quad * 8;
            bf16x8 bfrag[4];
#pragma unroll
            for (int ni = 0; ni < 4; ++ni)
                bfrag[ni] = *(const bf16x8*)&wk[(ni * 16 + l16) * 64 + kb];
#pragma unroll
            for (int ni = 0; ni < 4; ++ni)
                acc[ni] = __builtin_amdgcn_mfma_f32_16x16x32_bf16(
                    afrag[ks], bfrag[ni], acc[ni], 0, 0, 0);
        }
        // C/D layout: col = lane&15, row = quad*4 + reg
#pragma unroll
        for (int ni = 0; ni < 4; ++ni)
#pragma unroll
            for (int r = 0; r < 4; ++r) {
                int m = mrow + r;
                if (m < nNodes)
                    xwc[(size_t)m * SLABCOL + kk * 64 + ni * 16 + l16] =
                        __float2bfloat16(acc[ni][r]);
            }
    }
}

// ---------------------------------------------------------------------------
// Kernel 1b: xroot[n][d] = x @ root (fp32 out, MFMA)
// ---------------------------------------------------------------------------
__global__ __launch_bounds__(256) void gemm_root_kernel(
    const float* __restrict__ x, const __hip_bfloat16* __restrict__ rt,
    float* __restrict__ xroot, int nNodes) {
    __shared__ __attribute__((aligned(16))) __hip_bfloat16 As[128 * 72];

    const int tid  = threadIdx.x;
    const int wave = tid >> 6, lane = tid & 63;
    const int quad = lane >> 4, l16 = lane & 15;
    const int row0 = blockIdx.x * 128;

    for (int i = 0; i < 32; ++i) {
        int idx = tid + i * 256;
        int r = idx >> 6, c = idx & 63;
        float v = (row0 + r < nNodes) ? x[(size_t)(row0 + r) * CIN + c] : 0.f;
        As[r * 72 + c] = __float2bfloat16(v);
    }
    __syncthreads();

    f32x4 acc[2][4] = {};
#pragma unroll
    for (int ks = 0; ks < 2; ++ks) {
        int kb = ks * 32 + quad * 8;
        bf16x8 afrag[2], bfrag[4];
        for (int mi = 0; mi < 2; ++mi)
            afrag[mi] = *(const bf16x8*)&As[(wave * 32 + mi * 16 + l16) * 72 + kb];
        for (int ni = 0; ni < 4; ++ni)
            bfrag[ni] = *(const bf16x8*)&rt[(ni * 16 + l16) * 64 + kb];
        for (int mi = 0; mi < 2; ++mi)
            for (int ni = 0; ni < 4; ++ni)
                acc[mi][ni] = __builtin_amdgcn_mfma_f32_16x16x32_bf16(
                    afrag[mi], bfrag[ni], acc[mi][ni], 0, 0, 0);
    }
#pragma unroll
    for (int mi = 0; mi < 2; ++mi)
        for (int ni = 0; ni < 4; ++ni)
            for (int r = 0; r < 4; ++r) {
                int m = row0 + wave * 32 + mi * 16 + quad * 4 + r;
                if (m < nNodes)
                    xroot[(size_t)m * 64 + ni * 16 + l16] = acc[mi][ni][r];
            }
}

// ---------------------------------------------------------------------------
// Kernel 2: per-dst aggregation for one z-slab. One wave per dst.
// Active records are contiguous [lo,hi); zw switches at mid. Branch-free.
// ---------------------------------------------------------------------------
__global__ __launch_bounds__(256) void agg_kernel(
    const uint2* __restrict__ rec, const int* __restrict__ grpoff,
    const __hip_bfloat16* __restrict__ xwc, float* __restrict__ agg,
    int nNodes, int slab) {
    int dst  = (blockIdx.x * 256 + threadIdx.x) >> 6;
    int lane = threadIdx.x & 63;
    if (dst >= nNodes) return;

    int gl = slab > 0 ? slab - 1 : 0;
    int gh = slab < 3 ? slab + 1 : 3;
    int lo  = __builtin_amdgcn_readfirstlane(grpoff[dst * 4 + gl]);
    int mid = __builtin_amdgcn_readfirstlane(grpoff[dst * 4 + slab]);
    int hi  = __builtin_amdgcn_readfirstlane(grpoff[dst * 4 + gh]);

    const float qs = 1.f / 2048.f;
    float acc = 0.f;
    int j = lo;
    for (; j + 1 < hi; j += 2) {
        uint2 r0 = rec[j];
        uint2 r1 = rec[j + 1];
        const __hip_bfloat16* p0 =
            xwc + (size_t)(r0.x & 0x1ffffu) * SLABCOL + ((r0.x >> 17) & 15u) * 64 + lane;
        const __hip_bfloat16* p1 =
            xwc + (size_t)(r1.x & 0x1ffffu) * SLABCOL + ((r1.x >> 17) & 15u) * 64 + lane;
        float a00 = __bfloat162float(p0[0]);
        float a10 = __bfloat162float(p0[64]);
        float a01 = __bfloat162float(p0[256]);
        float a11 = __bfloat162float(p0[320]);
        float b00 = __bfloat162float(p1[0]);
        float b10 = __bfloat162float(p1[64]);
        float b01 = __bfloat162float(p1[256]);
        float b11 = __bfloat162float(p1[320]);

        float t2a = (float)(r0.x >> 21) * qs;
        float zwa = (j < mid) ? t2a : 1.f - t2a;
        float t0a = (float)(r0.y & 2047u) * qs;
        float t1a = (float)((r0.y >> 11) & 2047u) * qs;
        acc += zwa * ((1.f - t0a) * (1.f - t1a) * a00 + t0a * (1.f - t1a) * a10 +
                      (1.f - t0a) * t1a * a01 + t0a * t1a * a11);

        float t2b = (float)(r1.x >> 21) * qs;
        float zwb = (j + 1 < mid) ? t2b : 1.f - t2b;
        float t0b = (float)(r1.y & 2047u) * qs;
        float t1b = (float)((r1.y >> 11) & 2047u) * qs;
        acc += zwb * ((1.f - t0b) * (1.f - t1b) * b00 + t0b * (1.f - t1b) * b10 +
                      (1.f - t0b) * t1b * b01 + t0b * t1b * b11);
    }
    if (j < hi) {
        uint2 r0 = rec[j];
        const __hip_bfloat16* p0 =
            xwc + (size_t)(r0.x & 0x1ffffu) * SLABCOL + ((r0.x >> 17) & 15u) * 64 + lane;
        float a00 = __bfloat162float(p0[0]);
        float a10 = __bfloat162float(p0[64]);
        float a01 = __bfloat162float(p0[256]);
        float a11 = __bfloat162float(p0[320]);
        float t2a = (float)(r0.x >> 21) * qs;
        float zwa = (j < mid) ? t2a : 1.f - t2a;
        float t0a = (float)(r0.y & 2047u) * qs;
        float t1a = (float)((r0.y >> 11) & 2047u) * qs;
        acc += zwa * ((1.f - t0a) * (1.f - t1a) * a00 + t0a * (1.f - t1a) * a10 +
                      (1.f - t0a) * t1a * a01 + t0a * t1a * a11);
    }

    float* dp = &agg[(size_t)dst * COUT + lane];
    if (slab == 0) *dp = acc;
    else           *dp += acc;
}

// ---------------------------------------------------------------------------
// Kernel 3: h = elu(agg/max(deg,1) + xroot + bias); accumulate BN sums
// ---------------------------------------------------------------------------
__global__ __launch_bounds__(256) void node_kernel(
    const float* __restrict__ xroot, const float* __restrict__ agg,
    const int* __restrict__ grpoff, const float* __restrict__ bias,
    float* __restrict__ h, float* __restrict__ gstat, int nNodes) {
    __shared__ float red[8][64];
    int tid = threadIdx.x, wave = tid >> 6, lane = tid & 63;
    float b = bias[lane];
    float s = 0.f, s2 = 0.f;
    int total = nNodes * 64;
    for (int i = blockIdx.x * 256 + tid; i < total; i += gridDim.x * 256) {
        int n = i >> 6;
        float dn = fmaxf((float)(grpoff[4 * n + 3] - grpoff[4 * n]), 1.f);
        float acc = b + xroot[i] + agg[i] / dn;
        float hv = acc > 0.f ? acc : expm1f(acc);
        h[i] = hv;
        s += hv; s2 += hv * hv;
    }
    red[wave][lane] = s;
    red[4 + wave][lane] = s2;
    __syncthreads();
    if (tid < 64) {
        atomicAdd(&gstat[tid], red[0][tid] + red[1][tid] + red[2][tid] + red[3][tid]);
    } else if (tid < 128) {
        int d = tid - 64;
        atomicAdd(&gstat[64 + d], red[4][d] + red[5][d] + red[6][d] + red[7][d]);
    }
}

// ---------------------------------------------------------------------------
__global__ void stats_kernel(const float* __restrict__ gamma,
                             const float* __restrict__ beta,
                             float* __restrict__ gstat, int nNodes) {
    int d = threadIdx.x;
    float invn = 1.f / (float)nNodes;
    float mean = gstat[d] * invn;
    float var  = gstat[64 + d] * invn - mean * mean;
    float sc   = gamma[d] * rsqrtf(var + EPSV);
    gstat[128 + d] = sc;
    gstat[192 + d] = beta[d] - mean * sc;
}

__global__ __launch_bounds__(256) void initpool_kernel(unsigned* __restrict__ out, int total) {
    int i = blockIdx.x * 256 + threadIdx.x;
    if (i < total) out[i] = ENC_NEG_INF;
}

__global__ __launch_bounds__(256) void pool_kernel(
    const float* __restrict__ h, const float* __restrict__ pos,
    const int* __restrict__ batch, const float* __restrict__ gstat,
    unsigned* __restrict__ out, int nNodes) {
    int gid = blockIdx.x * 256 + threadIdx.x;
    int n = gid >> 6, d = gid & 63;
    if (n >= nNodes) return;
    float v = h[gid] * gstat[128 + d] + gstat[192 + d];
    int v0 = min(max((int)floorf(pos[n * 3 + 0] * (1.f / 32.f)), 0), 7);
    int v1 = min(max((int)floorf(pos[n * 3 + 1] * (1.f / 32.f)), 0), 7);
    int v2 = min(max((int)floorf(pos[n * 3 + 2] * (1.f / 32.f)), 0), 7);
    int cl = batch[n] * 512 + v0 * 64 + v1 * 8 + v2;
    atomicMax(&out[cl * 64 + d], encf(v));
}

__global__ __launch_bounds__(256) void decode_kernel(unsigned* __restrict__ out, int total) {
    int i = blockIdx.x * 256 + threadIdx.x;
    if (i >= total) return;
    float f = decf(out[i]);
    if (!isfinite(f)) f = 0.f;
    ((float*)out)[i] = f;
}

// ---------------------------------------------------------------------------
extern "C" void kernel_launch(void* const* d_in, const int* in_sizes, int n_in,
                              void* d_out, int out_size, void* d_ws, size_t ws_size,
                              hipStream_t stream) {
    const float* x     = (const float*)d_in[0];
    const int*   ei    = (const int*)d_in[1];
    const float* ea    = (const float*)d_in[2];
    const float* pos   = (const float*)d_in[3];
    const int*   batch = (const int*)d_in[4];
    const float* w     = (const float*)d_in[5];
    const float* root  = (const float*)d_in[6];
    const float* bias  = (const float*)d_in[7];
    const float* gamma = (const float*)d_in[8];
    const float* beta  = (const float*)d_in[9];

    const int N = in_sizes[0] / CIN;     // 50000
    const int E = in_sizes[1] / 2;       // 800000

    // workspace carve-up (~122 MB; h and xroot alias the dead xwc buffer)
    char* ws = (char*)d_ws;
    size_t off_b = 0;
    auto carve = [&](size_t bytes) -> char* {
        char* p = ws + off_b;
        off_b = (off_b + bytes + 255) & ~(size_t)255;
        return p;
    };
    __hip_bfloat16* xwc    = (__hip_bfloat16*)carve((size_t)N * SLABCOL * 2); // 102.4 MB
    __hip_bfloat16* wt     = (__hip_bfloat16*)carve((size_t)(NK + 1) * CIN * COUT * 2);
    float*          agg    = (float*)carve((size_t)N * COUT * 4);             // 12.8 MB
    int*            degz   = (int*)carve((size_t)N * 4 * 4);
    int*            grpoff = (int*)carve((size_t)N * 4 * 4);
    int*            cur4   = (int*)carve((size_t)N * 4 * 4);
    int*            psum   = (int*)carve(256 * 4);
    uint2*          rec    = (uint2*)carve((size_t)E * 8);                    // 6.4 MB
    float*          gst    = (float*)carve(256 * 4);
    float*          h      = (float*)xwc;
    float*          xroot  = (float*)((char*)xwc + ((size_t)N * COUT * 4 + 4096));
    __hip_bfloat16* rt     = wt + (size_t)NK * CIN * COUT;

    hipMemsetAsync(degz, 0, (size_t)N * 16, stream);
    hipMemsetAsync(gst, 0, 256 * 4, stream);

    transpose_w_kernel<<<(NK * CIN * COUT) / 256, 256, 0, stream>>>(w, wt);
    transpose_root_kernel<<<16, 256, 0, stream>>>(root, rt);

    // z-grouped CSR build
    const int nScan = (N + 1023) / 1024;
    hist_kernel<<<(E + 255) / 256, 256, 0, stream>>>(ei, ea, degz, E);
    scanA_kernel<<<nScan, 1024, 0, stream>>>((const int4*)degz, psum, N);
    scanB_kernel<<<1, 64, 0, stream>>>(psum, nScan);
    scanC_kernel<<<nScan, 1024, 0, stream>>>((const int4*)degz, psum, grpoff, cur4, N);
    scatter_kernel<<<(E + 255) / 256, 256, 0, stream>>>(ei, ea, cur4, rec, E);

    const int ggrid = (N + 63) / 64;          // 782 blocks
    const int agrid = (N * 64 + 255) / 256;   // one wave per dst
    for (int slab = 0; slab < 4; ++slab) {
        gemm_xw_kernel<<<ggrid, 256, 0, stream>>>(x, wt, xwc, N, slab * SLABK);
        agg_kernel<<<agrid, 256, 0, stream>>>(rec, grpoff, xwc, agg, N, slab);
    }

    gemm_root_kernel<<<(N + 127) / 128, 256, 0, stream>>>(x, rt, xroot, N);

    node_kernel<<<1024, 256, 0, stream>>>(xroot, agg, grpoff, bias, h, gst, N);

    stats_kernel<<<1, 64, 0, stream>>>(gamma, beta, gst, N);

    initpool_kernel<<<(out_size + 255) / 256, 256, 0, stream>>>((unsigned*)d_out, out_size);

    pool_kernel<<<((size_t)N * COUT + 255) / 256, 256, 0, stream>>>(
        h, pos, batch, gst, (unsigned*)d_out, N);

    decode_kernel<<<(out_size + 255) / 256, 256, 0, stream>>>((unsigned*)d_out, out_size);
}

// Round 6
// 607.194 us; speedup vs baseline: 1.1167x; 1.1132x over previous
//
#include <hip/hip_runtime.h>
#include <hip/hip_bf16.h>

typedef __attribute__((ext_vector_type(8))) short bf16x8;
typedef __attribute__((ext_vector_type(4))) float f32x4;

#define CIN 64
#define COUT 64
#define NK 64
#define SLABK 16             // kernels per z-slab (one kz plane, 4x4 xy)
#define SLABCOL 1024         // SLABK * COUT
#define EPSV 1e-5f
#define ENC_NEG_INF 0x007FFFFFu

__device__ __forceinline__ unsigned encf(float f) {
    unsigned b = __float_as_uint(f);
    return (b & 0x80000000u) ? ~b : (b | 0x80000000u);
}
__device__ __forceinline__ float decf(unsigned u) {
    unsigned b = (u & 0x80000000u) ? (u & 0x7FFFFFFFu) : ~u;
    return __uint_as_float(b);
}
__device__ __forceinline__ unsigned pack2bf(float a, float b) {
    unsigned ua = (unsigned)__bfloat16_as_ushort(__float2bfloat16(a));
    unsigned ub = (unsigned)__bfloat16_as_ushort(__float2bfloat16(b));
    return ua | (ub << 16);
}

// ---------------------------------------------------------------------------
// Kernel 0a: weight [k][c][d] fp32 -> fragment-swizzled bf16:
//   swz[k*4096 + ni*1024 + ks*512 + lane*8 + j] = W[k][c][d]
//   where quad=lane>>4, l16=lane&15, c = ks*32 + quad*8 + j, d = ni*16 + l16
// A-fragment load for (ni,ks) is then 64 lanes x 16 B fully contiguous.
// ---------------------------------------------------------------------------
__global__ __launch_bounds__(256) void swizzle_w_kernel(
    const float* __restrict__ w, __hip_bfloat16* __restrict__ swz) {
    int i = blockIdx.x * 256 + threadIdx.x;          // 262144 total
    int k  = i >> 12;
    int r  = i & 4095;
    int ni = r >> 10;
    int ks = (r >> 9) & 1;
    int lane = (r >> 3) & 63;
    int j  = r & 7;
    int quad = lane >> 4, l16 = lane & 15;
    int c = ks * 32 + quad * 8 + j;
    int d = ni * 16 + l16;
    swz[i] = __float2bfloat16(w[(k << 12) + (c << 6) + d]);
}

// Kernel 0b: root [c][d] fp32 -> same swizzle (single k)
__global__ __launch_bounds__(256) void swizzle_root_kernel(
    const float* __restrict__ root, __hip_bfloat16* __restrict__ rt) {
    int r = blockIdx.x * 256 + threadIdx.x;          // 4096 total
    int ni = r >> 10;
    int ks = (r >> 9) & 1;
    int lane = (r >> 3) & 63;
    int j  = r & 7;
    int quad = lane >> 4, l16 = lane & 15;
    int c = ks * 32 + quad * 8 + j;
    int d = ni * 16 + l16;
    rt[r] = __float2bfloat16(root[(c << 6) + d]);
}

// ---------------------------------------------------------------------------
// CSR build, z-grouped: per-dst per-l2i histogram -> scan -> scatter 8-B recs
// rec: x = src | base<<17 | q2<<21 ; y = q0 | q1<<11   (11-bit fixed t's)
// ---------------------------------------------------------------------------
__global__ __launch_bounds__(256) void hist_kernel(
    const int* __restrict__ ei, const float* __restrict__ ea,
    int* __restrict__ degz, int E) {
    int e = blockIdx.x * 256 + threadIdx.x;
    if (e >= E) return;
    int dst = ei[E + e];
    float f2 = ea[e * 3 + 2] * 3.f;
    int l2i = (int)fminf(fmaxf(floorf(f2), 0.f), 2.f);
    atomicAdd(&degz[dst * 4 + l2i], 1);
}

__global__ __launch_bounds__(1024) void scanA_kernel(
    const int4* __restrict__ degz, int* __restrict__ psum, int n) {
    __shared__ int s[1024];
    int i = blockIdx.x * 1024 + threadIdx.x;
    int v = 0;
    if (i < n) { int4 d = degz[i]; v = d.x + d.y + d.z; }
    s[threadIdx.x] = v;
    __syncthreads();
    for (int st = 512; st > 0; st >>= 1) {
        if (threadIdx.x < st) s[threadIdx.x] += s[threadIdx.x + st];
        __syncthreads();
    }
    if (threadIdx.x == 0) psum[blockIdx.x] = s[0];
}

__global__ void scanB_kernel(int* __restrict__ psum, int nb) {
    if (threadIdx.x == 0) {
        int run = 0;
        for (int b = 0; b < nb; ++b) { int v = psum[b]; psum[b] = run; run += v; }
    }
}

__global__ __launch_bounds__(1024) void scanC_kernel(
    const int4* __restrict__ degz, const int* __restrict__ psum,
    int* __restrict__ grpoff, int* __restrict__ cur4, int n) {
    __shared__ int s[1024];
    int tid = threadIdx.x, i = blockIdx.x * 1024 + tid;
    int4 d = make_int4(0, 0, 0, 0);
    if (i < n) d = degz[i];
    int v = d.x + d.y + d.z;
    s[tid] = v;
    for (int st = 1; st < 1024; st <<= 1) {
        __syncthreads();
        int t = (tid >= st) ? s[tid - st] : 0;
        __syncthreads();
        s[tid] += t;
    }
    __syncthreads();
    int excl = s[tid] - v + psum[blockIdx.x];
    if (i < n) {
        grpoff[4 * i + 0] = excl;
        grpoff[4 * i + 1] = excl + d.x;
        grpoff[4 * i + 2] = excl + d.x + d.y;
        grpoff[4 * i + 3] = excl + v;
        cur4[4 * i + 0] = excl;
        cur4[4 * i + 1] = excl + d.x;
        cur4[4 * i + 2] = excl + d.x + d.y;
    }
}

__global__ __launch_bounds__(256) void scatter_kernel(
    const int* __restrict__ ei, const float* __restrict__ ea,
    int* __restrict__ cur4, uint2* __restrict__ rec, int E) {
    int e = blockIdx.x * 256 + threadIdx.x;
    if (e >= E) return;
    int src = ei[e], dst = ei[E + e];
    float f0 = ea[e * 3 + 0] * 3.f;
    float f1 = ea[e * 3 + 1] * 3.f;
    float f2 = ea[e * 3 + 2] * 3.f;
    float l0 = fminf(fmaxf(floorf(f0), 0.f), 2.f);
    float l1 = fminf(fmaxf(floorf(f1), 0.f), 2.f);
    float l2 = fminf(fmaxf(floorf(f2), 0.f), 2.f);
    unsigned q0 = (unsigned)((f0 - l0) * 2048.f);
    unsigned q1 = (unsigned)((f1 - l1) * 2048.f);
    unsigned q2 = (unsigned)((f2 - l2) * 2048.f);
    int base = (int)l0 + 4 * (int)l1;
    int l2i = (int)l2;
    uint2 r;
    r.x = (unsigned)src | ((unsigned)base << 17) | (q2 << 21);
    r.y = q0 | (q1 << 11);
    int pos = atomicAdd(&cur4[dst * 4 + l2i], 1);
    rec[pos] = r;
}

// ---------------------------------------------------------------------------
// Kernel 1: slab GEMM, transposed operands: D[d][node] = W^T-frag x x-frag.
// Block = 64 nodes; wave owns 16 nodes (l16 = node), ni loops d-tiles.
// A (=W) fragments coalesced from swizzled wt; B (=x) staged in LDS once.
// Stores: packed uint2 (4 consecutive d per lane).
// ---------------------------------------------------------------------------
__global__ __launch_bounds__(256) void gemm_xw_kernel(
    const float* __restrict__ x, const __hip_bfloat16* __restrict__ wswz,
    __hip_bfloat16* __restrict__ xwc, int nNodes, int k0) {
    __shared__ __attribute__((aligned(16))) __hip_bfloat16 Bs[64 * 72];

    const int tid  = threadIdx.x;
    const int wave = tid >> 6, lane = tid & 63;
    const int quad = lane >> 4, l16 = lane & 15;
    const int row0 = blockIdx.x * 64;

    // stage x rows (64 x 64) fp32 -> bf16
    for (int i = 0; i < 16; ++i) {
        int idx = tid + i * 256;
        int r = idx >> 6, c = idx & 63;
        float v = (row0 + r < nNodes) ? x[(size_t)(row0 + r) * CIN + c] : 0.f;
        Bs[r * 72 + c] = __float2bfloat16(v);
    }
    __syncthreads();

    // B fragment (x) per lane: node = row0 + wave*16 + l16, k = ks*32+quad*8+j
    bf16x8 bfrag[2];
#pragma unroll
    for (int ks = 0; ks < 2; ++ks)
        bfrag[ks] = *(const bf16x8*)&Bs[(wave * 16 + l16) * 72 + ks * 32 + quad * 8];

    const int node = row0 + wave * 16 + l16;
    const bool valid = node < nNodes;
    __hip_bfloat16* orow = xwc + (size_t)node * SLABCOL;

    for (int kk = 0; kk < SLABK; ++kk) {
        const __hip_bfloat16* wk = wswz + (size_t)(k0 + kk) * 4096;
#pragma unroll
        for (int ni = 0; ni < 4; ++ni) {
            f32x4 acc = {};
#pragma unroll
            for (int ks = 0; ks < 2; ++ks) {
                bf16x8 afrag = *(const bf16x8*)&wk[ni * 1024 + ks * 512 + lane * 8];
                acc = __builtin_amdgcn_mfma_f32_16x16x32_bf16(afrag, bfrag[ks], acc, 0, 0, 0);
            }
            // D layout: col(lane&15)=node, row(quad*4+r)=d offset in tile
            if (valid) {
                uint2 pk;
                pk.x = pack2bf(acc[0], acc[1]);
                pk.y = pack2bf(acc[2], acc[3]);
                *(uint2*)&orow[kk * 64 + ni * 16 + quad * 4] = pk;
            }
        }
    }
}

// ---------------------------------------------------------------------------
// Kernel 1b: xroot[n][d] = x @ root, fp32 out, same transposed scheme.
// ---------------------------------------------------------------------------
__global__ __launch_bounds__(256) void gemm_root_kernel(
    const float* __restrict__ x, const __hip_bfloat16* __restrict__ rt,
    float* __restrict__ xroot, int nNodes) {
    __shared__ __attribute__((aligned(16))) __hip_bfloat16 Bs[64 * 72];

    const int tid  = threadIdx.x;
    const int wave = tid >> 6, lane = tid & 63;
    const int quad = lane >> 4, l16 = lane & 15;
    const int row0 = blockIdx.x * 64;

    for (int i = 0; i < 16; ++i) {
        int idx = tid + i * 256;
        int r = idx >> 6, c = idx & 63;
        float v = (row0 + r < nNodes) ? x[(size_t)(row0 + r) * CIN + c] : 0.f;
        Bs[r * 72 + c] = __float2bfloat16(v);
    }
    __syncthreads();

    bf16x8 bfrag[2];
#pragma unroll
    for (int ks = 0; ks < 2; ++ks)
        bfrag[ks] = *(const bf16x8*)&Bs[(wave * 16 + l16) * 72 + ks * 32 + quad * 8];

    const int node = row0 + wave * 16 + l16;
    const bool valid = node < nNodes;

#pragma unroll
    for (int ni = 0; ni < 4; ++ni) {
        f32x4 acc = {};
#pragma unroll
        for (int ks = 0; ks < 2; ++ks) {
            bf16x8 afrag = *(const bf16x8*)&rt[ni * 1024 + ks * 512 + lane * 8];
            acc = __builtin_amdgcn_mfma_f32_16x16x32_bf16(afrag, bfrag[ks], acc, 0, 0, 0);
        }
        if (valid)
            *(f32x4*)&xroot[(size_t)node * 64 + ni * 16 + quad * 4] = acc;
    }
}

// ---------------------------------------------------------------------------
// Kernel 2: per-dst aggregation for one z-slab. One wave per dst.
// Active records contiguous [lo,hi); zw switches at mid. Branch-free.
// ---------------------------------------------------------------------------
__global__ __launch_bounds__(256) void agg_kernel(
    const uint2* __restrict__ rec, const int* __restrict__ grpoff,
    const __hip_bfloat16* __restrict__ xwc, float* __restrict__ agg,
    int nNodes, int slab) {
    int dst  = (blockIdx.x * 256 + threadIdx.x) >> 6;
    int lane = threadIdx.x & 63;
    if (dst >= nNodes) return;

    int gl = slab > 0 ? slab - 1 : 0;
    int gh = slab < 3 ? slab + 1 : 3;
    int lo  = __builtin_amdgcn_readfirstlane(grpoff[dst * 4 + gl]);
    int mid = __builtin_amdgcn_readfirstlane(grpoff[dst * 4 + slab]);
    int hi  = __builtin_amdgcn_readfirstlane(grpoff[dst * 4 + gh]);

    const float qs = 1.f / 2048.f;
    float acc = 0.f;
    int j = lo;
    for (; j + 1 < hi; j += 2) {
        uint2 r0 = rec[j];
        uint2 r1 = rec[j + 1];
        const __hip_bfloat16* p0 =
            xwc + (size_t)(r0.x & 0x1ffffu) * SLABCOL + ((r0.x >> 17) & 15u) * 64 + lane;
        const __hip_bfloat16* p1 =
            xwc + (size_t)(r1.x & 0x1ffffu) * SLABCOL + ((r1.x >> 17) & 15u) * 64 + lane;
        float a00 = __bfloat162float(p0[0]);
        float a10 = __bfloat162float(p0[64]);
        float a01 = __bfloat162float(p0[256]);
        float a11 = __bfloat162float(p0[320]);
        float b00 = __bfloat162float(p1[0]);
        float b10 = __bfloat162float(p1[64]);
        float b01 = __bfloat162float(p1[256]);
        float b11 = __bfloat162float(p1[320]);

        float t2a = (float)(r0.x >> 21) * qs;
        float zwa = (j < mid) ? t2a : 1.f - t2a;
        float t0a = (float)(r0.y & 2047u) * qs;
        float t1a = (float)((r0.y >> 11) & 2047u) * qs;
        acc += zwa * ((1.f - t0a) * (1.f - t1a) * a00 + t0a * (1.f - t1a) * a10 +
                      (1.f - t0a) * t1a * a01 + t0a * t1a * a11);

        float t2b = (float)(r1.x >> 21) * qs;
        float zwb = (j + 1 < mid) ? t2b : 1.f - t2b;
        float t0b = (float)(r1.y & 2047u) * qs;
        float t1b = (float)((r1.y >> 11) & 2047u) * qs;
        acc += zwb * ((1.f - t0b) * (1.f - t1b) * b00 + t0b * (1.f - t1b) * b10 +
                      (1.f - t0b) * t1b * b01 + t0b * t1b * b11);
    }
    if (j < hi) {
        uint2 r0 = rec[j];
        const __hip_bfloat16* p0 =
            xwc + (size_t)(r0.x & 0x1ffffu) * SLABCOL + ((r0.x >> 17) & 15u) * 64 + lane;
        float a00 = __bfloat162float(p0[0]);
        float a10 = __bfloat162float(p0[64]);
        float a01 = __bfloat162float(p0[256]);
        float a11 = __bfloat162float(p0[320]);
        float t2a = (float)(r0.x >> 21) * qs;
        float zwa = (j < mid) ? t2a : 1.f - t2a;
        float t0a = (float)(r0.y & 2047u) * qs;
        float t1a = (float)((r0.y >> 11) & 2047u) * qs;
        acc += zwa * ((1.f - t0a) * (1.f - t1a) * a00 + t0a * (1.f - t1a) * a10 +
                      (1.f - t0a) * t1a * a01 + t0a * t1a * a11);
    }

    float* dp = &agg[(size_t)dst * COUT + lane];
    if (slab == 0) *dp = acc;
    else           *dp += acc;
}

// ---------------------------------------------------------------------------
// Kernel 3: h = elu(agg/max(deg,1) + xroot + bias); accumulate BN sums
// ---------------------------------------------------------------------------
__global__ __launch_bounds__(256) void node_kernel(
    const float* __restrict__ xroot, const float* __restrict__ agg,
    const int* __restrict__ grpoff, const float* __restrict__ bias,
    float* __restrict__ h, float* __restrict__ gstat, int nNodes) {
    __shared__ float red[8][64];
    int tid = threadIdx.x, wave = tid >> 6, lane = tid & 63;
    float b = bias[lane];
    float s = 0.f, s2 = 0.f;
    int total = nNodes * 64;
    for (int i = blockIdx.x * 256 + tid; i < total; i += gridDim.x * 256) {
        int n = i >> 6;
        float dn = fmaxf((float)(grpoff[4 * n + 3] - grpoff[4 * n]), 1.f);
        float acc = b + xroot[i] + agg[i] / dn;
        float hv = acc > 0.f ? acc : expm1f(acc);
        h[i] = hv;
        s += hv; s2 += hv * hv;
    }
    red[wave][lane] = s;
    red[4 + wave][lane] = s2;
    __syncthreads();
    if (tid < 64) {
        atomicAdd(&gstat[tid], red[0][tid] + red[1][tid] + red[2][tid] + red[3][tid]);
    } else if (tid < 128) {
        int d = tid - 64;
        atomicAdd(&gstat[64 + d], red[4][d] + red[5][d] + red[6][d] + red[7][d]);
    }
}

// ---------------------------------------------------------------------------
__global__ void stats_kernel(const float* __restrict__ gamma,
                             const float* __restrict__ beta,
                             float* __restrict__ gstat, int nNodes) {
    int d = threadIdx.x;
    float invn = 1.f / (float)nNodes;
    float mean = gstat[d] * invn;
    float var  = gstat[64 + d] * invn - mean * mean;
    float sc   = gamma[d] * rsqrtf(var + EPSV);
    gstat[128 + d] = sc;
    gstat[192 + d] = beta[d] - mean * sc;
}

__global__ __launch_bounds__(256) void initpool_kernel(unsigned* __restrict__ out, int total) {
    int i = blockIdx.x * 256 + threadIdx.x;
    if (i < total) out[i] = ENC_NEG_INF;
}

__global__ __launch_bounds__(256) void pool_kernel(
    const float* __restrict__ h, const float* __restrict__ pos,
    const int* __restrict__ batch, const float* __restrict__ gstat,
    unsigned* __restrict__ out, int nNodes) {
    int gid = blockIdx.x * 256 + threadIdx.x;
    int n = gid >> 6, d = gid & 63;
    if (n >= nNodes) return;
    float v = h[gid] * gstat[128 + d] + gstat[192 + d];
    int v0 = min(max((int)floorf(pos[n * 3 + 0] * (1.f / 32.f)), 0), 7);
    int v1 = min(max((int)floorf(pos[n * 3 + 1] * (1.f / 32.f)), 0), 7);
    int v2 = min(max((int)floorf(pos[n * 3 + 2] * (1.f / 32.f)), 0), 7);
    int cl = batch[n] * 512 + v0 * 64 + v1 * 8 + v2;
    atomicMax(&out[cl * 64 + d], encf(v));
}

__global__ __launch_bounds__(256) void decode_kernel(unsigned* __restrict__ out, int total) {
    int i = blockIdx.x * 256 + threadIdx.x;
    if (i >= total) return;
    float f = decf(out[i]);
    if (!isfinite(f)) f = 0.f;
    ((float*)out)[i] = f;
}

// ---------------------------------------------------------------------------
extern "C" void kernel_launch(void* const* d_in, const int* in_sizes, int n_in,
                              void* d_out, int out_size, void* d_ws, size_t ws_size,
                              hipStream_t stream) {
    const float* x     = (const float*)d_in[0];
    const int*   ei    = (const int*)d_in[1];
    const float* ea    = (const float*)d_in[2];
    const float* pos   = (const float*)d_in[3];
    const int*   batch = (const int*)d_in[4];
    const float* w     = (const float*)d_in[5];
    const float* root  = (const float*)d_in[6];
    const float* bias  = (const float*)d_in[7];
    const float* gamma = (const float*)d_in[8];
    const float* beta  = (const float*)d_in[9];

    const int N = in_sizes[0] / CIN;     // 50000
    const int E = in_sizes[1] / 2;       // 800000

    // workspace carve-up (~122 MB; h and xroot alias the dead xwc buffer)
    char* ws = (char*)d_ws;
    size_t off_b = 0;
    auto carve = [&](size_t bytes) -> char* {
        char* p = ws + off_b;
        off_b = (off_b + bytes + 255) & ~(size_t)255;
        return p;
    };
    __hip_bfloat16* xwc    = (__hip_bfloat16*)carve((size_t)N * SLABCOL * 2); // 102.4 MB
    __hip_bfloat16* wt     = (__hip_bfloat16*)carve((size_t)(NK + 1) * CIN * COUT * 2);
    float*          agg    = (float*)carve((size_t)N * COUT * 4);             // 12.8 MB
    int*            degz   = (int*)carve((size_t)N * 4 * 4);
    int*            grpoff = (int*)carve((size_t)N * 4 * 4);
    int*            cur4   = (int*)carve((size_t)N * 4 * 4);
    int*            psum   = (int*)carve(256 * 4);
    uint2*          rec    = (uint2*)carve((size_t)E * 8);                    // 6.4 MB
    float*          gst    = (float*)carve(256 * 4);
    float*          h      = (float*)xwc;
    float*          xroot  = (float*)((char*)xwc + ((size_t)N * COUT * 4 + 4096));
    __hip_bfloat16* rt     = wt + (size_t)NK * CIN * COUT;

    hipMemsetAsync(degz, 0, (size_t)N * 16, stream);
    hipMemsetAsync(gst, 0, 256 * 4, stream);

    swizzle_w_kernel<<<(NK * CIN * COUT) / 256, 256, 0, stream>>>(w, wt);
    swizzle_root_kernel<<<16, 256, 0, stream>>>(root, rt);

    // z-grouped CSR build
    const int nScan = (N + 1023) / 1024;
    hist_kernel<<<(E + 255) / 256, 256, 0, stream>>>(ei, ea, degz, E);
    scanA_kernel<<<nScan, 1024, 0, stream>>>((const int4*)degz, psum, N);
    scanB_kernel<<<1, 64, 0, stream>>>(psum, nScan);
    scanC_kernel<<<nScan, 1024, 0, stream>>>((const int4*)degz, psum, grpoff, cur4, N);
    scatter_kernel<<<(E + 255) / 256, 256, 0, stream>>>(ei, ea, cur4, rec, E);

    const int ggrid = (N + 63) / 64;          // 782 blocks
    const int agrid = (N * 64 + 255) / 256;   // one wave per dst
    for (int slab = 0; slab < 4; ++slab) {
        gemm_xw_kernel<<<ggrid, 256, 0, stream>>>(x, wt, xwc, N, slab * SLABK);
        agg_kernel<<<agrid, 256, 0, stream>>>(rec, grpoff, xwc, agg, N, slab);
    }

    gemm_root_kernel<<<ggrid, 256, 0, stream>>>(x, rt, xroot, N);

    node_kernel<<<1024, 256, 0, stream>>>(xroot, agg, grpoff, bias, h, gst, N);

    stats_kernel<<<1, 64, 0, stream>>>(gamma, beta, gst, N);

    initpool_kernel<<<(out_size + 255) / 256, 256, 0, stream>>>((unsigned*)d_out, out_size);

    pool_kernel<<<((size_t)N * COUT + 255) / 256, 256, 0, stream>>>(
        h, pos, batch, gst, (unsigned*)d_out, N);

    decode_kernel<<<(out_size + 255) / 256, 256, 0, stream>>>((unsigned*)d_out, out_size);
}

// Round 7
// 588.119 us; speedup vs baseline: 1.1530x; 1.0324x over previous
//
#include <hip/hip_runtime.h>
#include <hip/hip_bf16.h>

typedef __attribute__((ext_vector_type(8))) short bf16x8;
typedef __attribute__((ext_vector_type(4))) float f32x4;

#define CIN 64
#define COUT 64
#define NK 64
#define SLABK 16             // kernels per z-slab (one kz plane, 4x4 xy)
#define SLABCOL 1024         // SLABK * COUT
#define EPSV 1e-5f
#define ENC_NEG_INF 0x007FFFFFu
#define GEMM_GX 128          // node-group blocks per kk-group

__device__ __forceinline__ unsigned encf(float f) {
    unsigned b = __float_as_uint(f);
    return (b & 0x80000000u) ? ~b : (b | 0x80000000u);
}
__device__ __forceinline__ float decf(unsigned u) {
    unsigned b = (u & 0x80000000u) ? (u & 0x7FFFFFFFu) : ~u;
    return __uint_as_float(b);
}
__device__ __forceinline__ unsigned pack2bf(float a, float b) {
    unsigned ua = (unsigned)__bfloat16_as_ushort(__float2bfloat16(a));
    unsigned ub = (unsigned)__bfloat16_as_ushort(__float2bfloat16(b));
    return ua | (ub << 16);
}

// ---------------------------------------------------------------------------
// Kernel 0a: weight [k][c][d] fp32 -> fragment-swizzled bf16:
//   swz[k*4096 + ni*1024 + ks*512 + lane*8 + j] = W[k][c][d]
//   quad=lane>>4, l16=lane&15, c = ks*32 + quad*8 + j, d = ni*16 + l16
// ---------------------------------------------------------------------------
__global__ __launch_bounds__(256) void swizzle_w_kernel(
    const float* __restrict__ w, __hip_bfloat16* __restrict__ swz) {
    int i = blockIdx.x * 256 + threadIdx.x;          // 262144 total
    int k  = i >> 12;
    int r  = i & 4095;
    int ni = r >> 10;
    int ks = (r >> 9) & 1;
    int lane = (r >> 3) & 63;
    int j  = r & 7;
    int quad = lane >> 4, l16 = lane & 15;
    int c = ks * 32 + quad * 8 + j;
    int d = ni * 16 + l16;
    swz[i] = __float2bfloat16(w[(k << 12) + (c << 6) + d]);
}

// Kernel 0b: root [c][d] fp32 -> same swizzle (single k)
__global__ __launch_bounds__(256) void swizzle_root_kernel(
    const float* __restrict__ root, __hip_bfloat16* __restrict__ rt) {
    int r = blockIdx.x * 256 + threadIdx.x;          // 4096 total
    int ni = r >> 10;
    int ks = (r >> 9) & 1;
    int lane = (r >> 3) & 63;
    int j  = r & 7;
    int quad = lane >> 4, l16 = lane & 15;
    int c = ks * 32 + quad * 8 + j;
    int d = ni * 16 + l16;
    rt[r] = __float2bfloat16(root[(c << 6) + d]);
}

// ---------------------------------------------------------------------------
// CSR build, z-grouped: per-dst per-l2i histogram -> scan -> scatter 8-B recs
// rec: x = src | base<<17 | q2<<21 ; y = q0 | q1<<11   (11-bit fixed t's)
// ---------------------------------------------------------------------------
__global__ __launch_bounds__(256) void hist_kernel(
    const int* __restrict__ ei, const float* __restrict__ ea,
    int* __restrict__ degz, int E) {
    int e = blockIdx.x * 256 + threadIdx.x;
    if (e >= E) return;
    int dst = ei[E + e];
    float f2 = ea[e * 3 + 2] * 3.f;
    int l2i = (int)fminf(fmaxf(floorf(f2), 0.f), 2.f);
    atomicAdd(&degz[dst * 4 + l2i], 1);
}

__global__ __launch_bounds__(1024) void scanA_kernel(
    const int4* __restrict__ degz, int* __restrict__ psum, int n) {
    __shared__ int s[1024];
    int i = blockIdx.x * 1024 + threadIdx.x;
    int v = 0;
    if (i < n) { int4 d = degz[i]; v = d.x + d.y + d.z; }
    s[threadIdx.x] = v;
    __syncthreads();
    for (int st = 512; st > 0; st >>= 1) {
        if (threadIdx.x < st) s[threadIdx.x] += s[threadIdx.x + st];
        __syncthreads();
    }
    if (threadIdx.x == 0) psum[blockIdx.x] = s[0];
}

__global__ void scanB_kernel(int* __restrict__ psum, int nb) {
    if (threadIdx.x == 0) {
        int run = 0;
        for (int b = 0; b < nb; ++b) { int v = psum[b]; psum[b] = run; run += v; }
    }
}

__global__ __launch_bounds__(1024) void scanC_kernel(
    const int4* __restrict__ degz, const int* __restrict__ psum,
    int* __restrict__ grpoff, int* __restrict__ cur4, int n) {
    __shared__ int s[1024];
    int tid = threadIdx.x, i = blockIdx.x * 1024 + tid;
    int4 d = make_int4(0, 0, 0, 0);
    if (i < n) d = degz[i];
    int v = d.x + d.y + d.z;
    s[tid] = v;
    for (int st = 1; st < 1024; st <<= 1) {
        __syncthreads();
        int t = (tid >= st) ? s[tid - st] : 0;
        __syncthreads();
        s[tid] += t;
    }
    __syncthreads();
    int excl = s[tid] - v + psum[blockIdx.x];
    if (i < n) {
        grpoff[4 * i + 0] = excl;
        grpoff[4 * i + 1] = excl + d.x;
        grpoff[4 * i + 2] = excl + d.x + d.y;
        grpoff[4 * i + 3] = excl + v;
        cur4[4 * i + 0] = excl;
        cur4[4 * i + 1] = excl + d.x;
        cur4[4 * i + 2] = excl + d.x + d.y;
    }
}

__global__ __launch_bounds__(256) void scatter_kernel(
    const int* __restrict__ ei, const float* __restrict__ ea,
    int* __restrict__ cur4, uint2* __restrict__ rec, int E) {
    int e = blockIdx.x * 256 + threadIdx.x;
    if (e >= E) return;
    int src = ei[e], dst = ei[E + e];
    float f0 = ea[e * 3 + 0] * 3.f;
    float f1 = ea[e * 3 + 1] * 3.f;
    float f2 = ea[e * 3 + 2] * 3.f;
    float l0 = fminf(fmaxf(floorf(f0), 0.f), 2.f);
    float l1 = fminf(fmaxf(floorf(f1), 0.f), 2.f);
    float l2 = fminf(fmaxf(floorf(f2), 0.f), 2.f);
    unsigned q0 = (unsigned)((f0 - l0) * 2048.f);
    unsigned q1 = (unsigned)((f1 - l1) * 2048.f);
    unsigned q2 = (unsigned)((f2 - l2) * 2048.f);
    int base = (int)l0 + 4 * (int)l1;
    int l2i = (int)l2;
    uint2 r;
    r.x = (unsigned)src | ((unsigned)base << 17) | (q2 << 21);
    r.y = q0 | (q1 << 11);
    int pos = atomicAdd(&cur4[dst * 4 + l2i], 1);
    rec[pos] = r;
}

// ---------------------------------------------------------------------------
// Kernel 1: slab GEMM, register-resident weights, streaming nodes.
// grid = (GEMM_GX node-groups, 4 kk-groups). Block stages its kk-group's
// 32 KB of swizzled weights into LDS once; each wave pulls its 32 fragments
// into VGPRs once, then grid-strides over 16-node tiles:
// guarded float4 x-loads -> cvt bf16 -> 32 reg-only MFMAs -> 16 packed stores.
// ---------------------------------------------------------------------------
__global__ __launch_bounds__(256, 2) void gemm_xw_kernel(
    const float* __restrict__ x, const __hip_bfloat16* __restrict__ wswz,
    __hip_bfloat16* __restrict__ xwc, int nNodes, int k0) {
    __shared__ __attribute__((aligned(16))) __hip_bfloat16 Ws[4 * 4096];

    const int tid  = threadIdx.x;
    const int wave = tid >> 6, lane = tid & 63;
    const int quad = lane >> 4, l16 = lane & 15;
    const int kkg  = blockIdx.y;            // kk-group: kk = kkg*4 .. kkg*4+3

    // stage 4 kernels' swizzled weights (16384 bf16 = 32 KB) into LDS
    const __hip_bfloat16* wg = wswz + (size_t)(k0 + kkg * 4) * 4096;
    for (int i = 0; i < 8; ++i) {
        int idx = (tid + i * 256) * 8;      // 2048 chunks of 8 bf16
        *(bf16x8*)&Ws[idx] = *(const bf16x8*)&wg[idx];
    }
    __syncthreads();

    // pull the wave's 32 fragments LDS -> VGPRs (held across all tiles)
    bf16x8 wf[4][4][2];
#pragma unroll
    for (int kk2 = 0; kk2 < 4; ++kk2)
#pragma unroll
        for (int ni = 0; ni < 4; ++ni)
#pragma unroll
            for (int ks = 0; ks < 2; ++ks)
                wf[kk2][ni][ks] =
                    *(const bf16x8*)&Ws[kk2 * 4096 + ni * 1024 + ks * 512 + lane * 8];

    const int tilesTotal = (nNodes + 15) >> 4;
    const int gw = blockIdx.x * 4 + wave;
    const int stride = GEMM_GX * 4;
    const float4 zero4 = {0.f, 0.f, 0.f, 0.f};

    for (int t = gw; t < tilesTotal; t += stride) {
        int node = t * 16 + l16;
        bool valid = node < nNodes;
        const float* xp = x + (size_t)node * CIN + quad * 8;
        float4 a0 = valid ? *(const float4*)(xp)      : zero4;
        float4 a1 = valid ? *(const float4*)(xp + 4)  : zero4;
        float4 b0 = valid ? *(const float4*)(xp + 32) : zero4;
        float4 b1 = valid ? *(const float4*)(xp + 36) : zero4;
        bf16x8 bf[2];
        bf[0][0] = (short)__bfloat16_as_ushort(__float2bfloat16(a0.x));
        bf[0][1] = (short)__bfloat16_as_ushort(__float2bfloat16(a0.y));
        bf[0][2] = (short)__bfloat16_as_ushort(__float2bfloat16(a0.z));
        bf[0][3] = (short)__bfloat16_as_ushort(__float2bfloat16(a0.w));
        bf[0][4] = (short)__bfloat16_as_ushort(__float2bfloat16(a1.x));
        bf[0][5] = (short)__bfloat16_as_ushort(__float2bfloat16(a1.y));
        bf[0][6] = (short)__bfloat16_as_ushort(__float2bfloat16(a1.z));
        bf[0][7] = (short)__bfloat16_as_ushort(__float2bfloat16(a1.w));
        bf[1][0] = (short)__bfloat16_as_ushort(__float2bfloat16(b0.x));
        bf[1][1] = (short)__bfloat16_as_ushort(__float2bfloat16(b0.y));
        bf[1][2] = (short)__bfloat16_as_ushort(__float2bfloat16(b0.z));
        bf[1][3] = (short)__bfloat16_as_ushort(__float2bfloat16(b0.w));
        bf[1][4] = (short)__bfloat16_as_ushort(__float2bfloat16(b1.x));
        bf[1][5] = (short)__bfloat16_as_ushort(__float2bfloat16(b1.y));
        bf[1][6] = (short)__bfloat16_as_ushort(__float2bfloat16(b1.z));
        bf[1][7] = (short)__bfloat16_as_ushort(__float2bfloat16(b1.w));

        __hip_bfloat16* orow = xwc + (size_t)node * SLABCOL;
#pragma unroll
        for (int kk2 = 0; kk2 < 4; ++kk2) {
#pragma unroll
            for (int ni = 0; ni < 4; ++ni) {
                f32x4 acc = {};
                acc = __builtin_amdgcn_mfma_f32_16x16x32_bf16(wf[kk2][ni][0], bf[0], acc, 0, 0, 0);
                acc = __builtin_amdgcn_mfma_f32_16x16x32_bf16(wf[kk2][ni][1], bf[1], acc, 0, 0, 0);
                if (valid) {
                    uint2 pk;
                    pk.x = pack2bf(acc[0], acc[1]);
                    pk.y = pack2bf(acc[2], acc[3]);
                    *(uint2*)&orow[(kkg * 4 + kk2) * 64 + ni * 16 + quad * 4] = pk;
                }
            }
        }
    }
}

// ---------------------------------------------------------------------------
// Kernel 1b: xroot[n][d] = x @ root, fp32 out, transposed scheme.
// ---------------------------------------------------------------------------
__global__ __launch_bounds__(256) void gemm_root_kernel(
    const float* __restrict__ x, const __hip_bfloat16* __restrict__ rt,
    float* __restrict__ xroot, int nNodes) {
    __shared__ __attribute__((aligned(16))) __hip_bfloat16 Bs[64 * 72];

    const int tid  = threadIdx.x;
    const int wave = tid >> 6, lane = tid & 63;
    const int quad = lane >> 4, l16 = lane & 15;
    const int row0 = blockIdx.x * 64;

    for (int i = 0; i < 16; ++i) {
        int idx = tid + i * 256;
        int r = idx >> 6, c = idx & 63;
        float v = (row0 + r < nNodes) ? x[(size_t)(row0 + r) * CIN + c] : 0.f;
        Bs[r * 72 + c] = __float2bfloat16(v);
    }
    __syncthreads();

    bf16x8 bfrag[2];
#pragma unroll
    for (int ks = 0; ks < 2; ++ks)
        bfrag[ks] = *(const bf16x8*)&Bs[(wave * 16 + l16) * 72 + ks * 32 + quad * 8];

    const int node = row0 + wave * 16 + l16;
    const bool valid = node < nNodes;

#pragma unroll
    for (int ni = 0; ni < 4; ++ni) {
        f32x4 acc = {};
#pragma unroll
        for (int ks = 0; ks < 2; ++ks) {
            bf16x8 afrag = *(const bf16x8*)&rt[ni * 1024 + ks * 512 + lane * 8];
            acc = __builtin_amdgcn_mfma_f32_16x16x32_bf16(afrag, bfrag[ks], acc, 0, 0, 0);
        }
        if (valid)
            *(f32x4*)&xroot[(size_t)node * 64 + ni * 16 + quad * 4] = acc;
    }
}

// ---------------------------------------------------------------------------
// Kernel 2: per-dst aggregation for one z-slab. One wave per dst.
// Active records contiguous [lo,hi); zw switches at mid. Branch-free.
// ---------------------------------------------------------------------------
__global__ __launch_bounds__(256) void agg_kernel(
    const uint2* __restrict__ rec, const int* __restrict__ grpoff,
    const __hip_bfloat16* __restrict__ xwc, float* __restrict__ agg,
    int nNodes, int slab) {
    int dst  = (blockIdx.x * 256 + threadIdx.x) >> 6;
    int lane = threadIdx.x & 63;
    if (dst >= nNodes) return;

    int gl = slab > 0 ? slab - 1 : 0;
    int gh = slab < 3 ? slab + 1 : 3;
    int lo  = __builtin_amdgcn_readfirstlane(grpoff[dst * 4 + gl]);
    int mid = __builtin_amdgcn_readfirstlane(grpoff[dst * 4 + slab]);
    int hi  = __builtin_amdgcn_readfirstlane(grpoff[dst * 4 + gh]);

    const float qs = 1.f / 2048.f;
    float acc = 0.f;
    int j = lo;
    for (; j + 1 < hi; j += 2) {
        uint2 r0 = rec[j];
        uint2 r1 = rec[j + 1];
        const __hip_bfloat16* p0 =
            xwc + (size_t)(r0.x & 0x1ffffu) * SLABCOL + ((r0.x >> 17) & 15u) * 64 + lane;
        const __hip_bfloat16* p1 =
            xwc + (size_t)(r1.x & 0x1ffffu) * SLABCOL + ((r1.x >> 17) & 15u) * 64 + lane;
        float a00 = __bfloat162float(p0[0]);
        float a10 = __bfloat162float(p0[64]);
        float a01 = __bfloat162float(p0[256]);
        float a11 = __bfloat162float(p0[320]);
        float b00 = __bfloat162float(p1[0]);
        float b10 = __bfloat162float(p1[64]);
        float b01 = __bfloat162float(p1[256]);
        float b11 = __bfloat162float(p1[320]);

        float t2a = (float)(r0.x >> 21) * qs;
        float zwa = (j < mid) ? t2a : 1.f - t2a;
        float t0a = (float)(r0.y & 2047u) * qs;
        float t1a = (float)((r0.y >> 11) & 2047u) * qs;
        acc += zwa * ((1.f - t0a) * (1.f - t1a) * a00 + t0a * (1.f - t1a) * a10 +
                      (1.f - t0a) * t1a * a01 + t0a * t1a * a11);

        float t2b = (float)(r1.x >> 21) * qs;
        float zwb = (j + 1 < mid) ? t2b : 1.f - t2b;
        float t0b = (float)(r1.y & 2047u) * qs;
        float t1b = (float)((r1.y >> 11) & 2047u) * qs;
        acc += zwb * ((1.f - t0b) * (1.f - t1b) * b00 + t0b * (1.f - t1b) * b10 +
                      (1.f - t0b) * t1b * b01 + t0b * t1b * b11);
    }
    if (j < hi) {
        uint2 r0 = rec[j];
        const __hip_bfloat16* p0 =
            xwc + (size_t)(r0.x & 0x1ffffu) * SLABCOL + ((r0.x >> 17) & 15u) * 64 + lane;
        float a00 = __bfloat162float(p0[0]);
        float a10 = __bfloat162float(p0[64]);
        float a01 = __bfloat162float(p0[256]);
        float a11 = __bfloat162float(p0[320]);
        float t2a = (float)(r0.x >> 21) * qs;
        float zwa = (j < mid) ? t2a : 1.f - t2a;
        float t0a = (float)(r0.y & 2047u) * qs;
        float t1a = (float)((r0.y >> 11) & 2047u) * qs;
        acc += zwa * ((1.f - t0a) * (1.f - t1a) * a00 + t0a * (1.f - t1a) * a10 +
                      (1.f - t0a) * t1a * a01 + t0a * t1a * a11);
    }

    float* dp = &agg[(size_t)dst * COUT + lane];
    if (slab == 0) *dp = acc;
    else           *dp += acc;
}

// ---------------------------------------------------------------------------
// Kernel 3: h = elu(agg/max(deg,1) + xroot + bias); accumulate BN sums
// ---------------------------------------------------------------------------
__global__ __launch_bounds__(256) void node_kernel(
    const float* __restrict__ xroot, const float* __restrict__ agg,
    const int* __restrict__ grpoff, const float* __restrict__ bias,
    float* __restrict__ h, float* __restrict__ gstat, int nNodes) {
    __shared__ float red[8][64];
    int tid = threadIdx.x, wave = tid >> 6, lane = tid & 63;
    float b = bias[lane];
    float s = 0.f, s2 = 0.f;
    int total = nNodes * 64;
    for (int i = blockIdx.x * 256 + tid; i < total; i += gridDim.x * 256) {
        int n = i >> 6;
        float dn = fmaxf((float)(grpoff[4 * n + 3] - grpoff[4 * n]), 1.f);
        float acc = b + xroot[i] + agg[i] / dn;
        float hv = acc > 0.f ? acc : expm1f(acc);
        h[i] = hv;
        s += hv; s2 += hv * hv;
    }
    red[wave][lane] = s;
    red[4 + wave][lane] = s2;
    __syncthreads();
    if (tid < 64) {
        atomicAdd(&gstat[tid], red[0][tid] + red[1][tid] + red[2][tid] + red[3][tid]);
    } else if (tid < 128) {
        int d = tid - 64;
        atomicAdd(&gstat[64 + d], red[4][d] + red[5][d] + red[6][d] + red[7][d]);
    }
}

// ---------------------------------------------------------------------------
__global__ void stats_kernel(const float* __restrict__ gamma,
                             const float* __restrict__ beta,
                             float* __restrict__ gstat, int nNodes) {
    int d = threadIdx.x;
    float invn = 1.f / (float)nNodes;
    float mean = gstat[d] * invn;
    float var  = gstat[64 + d] * invn - mean * mean;
    float sc   = gamma[d] * rsqrtf(var + EPSV);
    gstat[128 + d] = sc;
    gstat[192 + d] = beta[d] - mean * sc;
}

__global__ __launch_bounds__(256) void initpool_kernel(unsigned* __restrict__ out, int total) {
    int i = blockIdx.x * 256 + threadIdx.x;
    if (i < total) out[i] = ENC_NEG_INF;
}

__global__ __launch_bounds__(256) void pool_kernel(
    const float* __restrict__ h, const float* __restrict__ pos,
    const int* __restrict__ batch, const float* __restrict__ gstat,
    unsigned* __restrict__ out, int nNodes) {
    int gid = blockIdx.x * 256 + threadIdx.x;
    int n = gid >> 6, d = gid & 63;
    if (n >= nNodes) return;
    float v = h[gid] * gstat[128 + d] + gstat[192 + d];
    int v0 = min(max((int)floorf(pos[n * 3 + 0] * (1.f / 32.f)), 0), 7);
    int v1 = min(max((int)floorf(pos[n * 3 + 1] * (1.f / 32.f)), 0), 7);
    int v2 = min(max((int)floorf(pos[n * 3 + 2] * (1.f / 32.f)), 0), 7);
    int cl = batch[n] * 512 + v0 * 64 + v1 * 8 + v2;
    atomicMax(&out[cl * 64 + d], encf(v));
}

__global__ __launch_bounds__(256) void decode_kernel(unsigned* __restrict__ out, int total) {
    int i = blockIdx.x * 256 + threadIdx.x;
    if (i >= total) return;
    float f = decf(out[i]);
    if (!isfinite(f)) f = 0.f;
    ((float*)out)[i] = f;
}

// ---------------------------------------------------------------------------
extern "C" void kernel_launch(void* const* d_in, const int* in_sizes, int n_in,
                              void* d_out, int out_size, void* d_ws, size_t ws_size,
                              hipStream_t stream) {
    const float* x     = (const float*)d_in[0];
    const int*   ei    = (const int*)d_in[1];
    const float* ea    = (const float*)d_in[2];
    const float* pos   = (const float*)d_in[3];
    const int*   batch = (const int*)d_in[4];
    const float* w     = (const float*)d_in[5];
    const float* root  = (const float*)d_in[6];
    const float* bias  = (const float*)d_in[7];
    const float* gamma = (const float*)d_in[8];
    const float* beta  = (const float*)d_in[9];

    const int N = in_sizes[0] / CIN;     // 50000
    const int E = in_sizes[1] / 2;       // 800000

    // workspace carve-up (~122 MB; h and xroot alias the dead xwc buffer)
    char* ws = (char*)d_ws;
    size_t off_b = 0;
    auto carve = [&](size_t bytes) -> char* {
        char* p = ws + off_b;
        off_b = (off_b + bytes + 255) & ~(size_t)255;
        return p;
    };
    __hip_bfloat16* xwc    = (__hip_bfloat16*)carve((size_t)N * SLABCOL * 2); // 102.4 MB
    __hip_bfloat16* wt     = (__hip_bfloat16*)carve((size_t)(NK + 1) * CIN * COUT * 2);
    float*          agg    = (float*)carve((size_t)N * COUT * 4);             // 12.8 MB
    int*            degz   = (int*)carve((size_t)N * 4 * 4);
    int*            grpoff = (int*)carve((size_t)N * 4 * 4);
    int*            cur4   = (int*)carve((size_t)N * 4 * 4);
    int*            psum   = (int*)carve(256 * 4);
    uint2*          rec    = (uint2*)carve((size_t)E * 8);                    // 6.4 MB
    float*          gst    = (float*)carve(256 * 4);
    float*          h      = (float*)xwc;
    float*          xroot  = (float*)((char*)xwc + ((size_t)N * COUT * 4 + 4096));
    __hip_bfloat16* rt     = wt + (size_t)NK * CIN * COUT;

    hipMemsetAsync(degz, 0, (size_t)N * 16, stream);
    hipMemsetAsync(gst, 0, 256 * 4, stream);

    swizzle_w_kernel<<<(NK * CIN * COUT) / 256, 256, 0, stream>>>(w, wt);
    swizzle_root_kernel<<<16, 256, 0, stream>>>(root, rt);

    // z-grouped CSR build
    const int nScan = (N + 1023) / 1024;
    hist_kernel<<<(E + 255) / 256, 256, 0, stream>>>(ei, ea, degz, E);
    scanA_kernel<<<nScan, 1024, 0, stream>>>((const int4*)degz, psum, N);
    scanB_kernel<<<1, 64, 0, stream>>>(psum, nScan);
    scanC_kernel<<<nScan, 1024, 0, stream>>>((const int4*)degz, psum, grpoff, cur4, N);
    scatter_kernel<<<(E + 255) / 256, 256, 0, stream>>>(ei, ea, cur4, rec, E);

    const dim3 ggrid(GEMM_GX, 4);             // node-groups x kk-groups
    const int agrid = (N * 64 + 255) / 256;   // one wave per dst
    for (int slab = 0; slab < 4; ++slab) {
        gemm_xw_kernel<<<ggrid, 256, 0, stream>>>(x, wt, xwc, N, slab * SLABK);
        agg_kernel<<<agrid, 256, 0, stream>>>(rec, grpoff, xwc, agg, N, slab);
    }

    gemm_root_kernel<<<(N + 63) / 64, 256, 0, stream>>>(x, rt, xroot, N);

    node_kernel<<<1024, 256, 0, stream>>>(xroot, agg, grpoff, bias, h, gst, N);

    stats_kernel<<<1, 64, 0, stream>>>(gamma, beta, gst, N);

    initpool_kernel<<<(out_size + 255) / 256, 256, 0, stream>>>((unsigned*)d_out, out_size);

    pool_kernel<<<((size_t)N * COUT + 255) / 256, 256, 0, stream>>>(
        h, pos, batch, gst, (unsigned*)d_out, N);

    decode_kernel<<<(out_size + 255) / 256, 256, 0, stream>>>((unsigned*)d_out, out_size);
}